// Round 1
// baseline (319.511 us; speedup 1.0000x reference)
//
#include <hip/hip_runtime.h>
#include <math.h>

#define NN 1152
#define DD 64
#define NSK 2016
#define NB 16
#define NROWS (NB*1024)
#define GPARTS 6
#define QPB 4
#define VPB (NSK/QPB)   // 504 vproj blocks

typedef short bf16x8 __attribute__((ext_vector_type(8)));
typedef short bf16x4 __attribute__((ext_vector_type(4)));
typedef float f32x4  __attribute__((ext_vector_type(4)));

__device__ __forceinline__ short bfr(float f){
  unsigned u = __float_as_uint(f);
  u += 0x7fffu + ((u >> 16) & 1u);
  return (short)(u >> 16);
}

// ================= K1: vproj (wave-per-q, silu staged once per block) + partial gram ==========
__global__ __launch_bounds__(256) void k_pre(const float* __restrict__ cond, const float* __restrict__ W,
                                             const float* __restrict__ bias, float* __restrict__ v,
                                             const float* __restrict__ P, float* __restrict__ Gpart){
  __shared__ float smem[16*1160];   // vproj: silu(cond) [16][1160-padded]; gram: Ps[64][68]
  const int tid = threadIdx.x;
  if (blockIdx.x < VPB){
    // ---- stage silu(cond) once per block (shared by 4 q-waves)
    #pragma unroll
    for (int b = 0; b < NB; ++b){
      for (int c = tid; c < NN; c += 256){
        const float xv = cond[b*NN + c];
        smem[b*1160 + c] = xv / (1.f + __expf(-xv));
      }
    }
    __syncthreads();
    const int lane = tid & 63, wid = tid >> 6;
    const int q = blockIdx.x * QPB + wid;
    float acc[NB];
    #pragma unroll
    for (int b = 0; b < NB; ++b) acc[b] = 0.f;
    for (int c0 = 0; c0 < NN; c0 += 256){
      const int c = c0 + lane*4;
      if (c < NN){
        const float4 wv = *(const float4*)&W[q*NN + c];
        #pragma unroll
        for (int b = 0; b < NB; ++b){
          const float4 sv = *(const float4*)&smem[b*1160 + c];
          acc[b] = fmaf(wv.x, sv.x, acc[b]);
          acc[b] = fmaf(wv.y, sv.y, acc[b]);
          acc[b] = fmaf(wv.z, sv.z, acc[b]);
          acc[b] = fmaf(wv.w, sv.w, acc[b]);
        }
      }
    }
    #pragma unroll
    for (int off = 32; off > 0; off >>= 1){
      #pragma unroll
      for (int b = 0; b < NB; ++b) acc[b] += __shfl_xor(acc[b], off);
    }
    if (lane == 0){
      const float bq = bias[q];
      #pragma unroll
      for (int b = 0; b < NB; ++b) v[b*NSK + q] = acc[b] + bq;
    }
  } else {
    // ---- partial gram: block p covers rows p*192 .. p*192+191 (3 chunks of 64)
    float* Ps = smem;
    const int p = blockIdx.x - VPB;
    const int lr = tid >> 4, lc = (tid & 15) * 4;
    const int ti = tid >> 4, tj = tid & 15;
    float acc[4][4];
    #pragma unroll
    for (int i=0;i<4;++i){
      #pragma unroll
      for (int j=0;j<4;++j) acc[i][j]=0.f;
    }
    for (int ch = 0; ch < 3; ++ch){
      const int n0 = p*192 + ch*64;
      __syncthreads();
      #pragma unroll
      for (int ii = 0; ii < 4; ++ii){
        const float4 pv = *(const float4*)&P[(n0 + lr + 16*ii)*DD + lc];
        *(float4*)&Ps[(lr + 16*ii)*68 + lc] = pv;
      }
      __syncthreads();
      for (int r = 0; r < 64; ++r){
        const float4 a = *(const float4*)&Ps[r*68 + ti*4];
        const float4 b = *(const float4*)&Ps[r*68 + tj*4];
        const float av[4] = {a.x,a.y,a.z,a.w};
        const float bv[4] = {b.x,b.y,b.z,b.w};
        #pragma unroll
        for (int i=0;i<4;++i){
          #pragma unroll
          for (int j=0;j<4;++j) acc[i][j] = fmaf(av[i], bv[j], acc[i][j]);
        }
      }
    }
    float* g = &Gpart[p*DD*DD];
    #pragma unroll
    for (int i=0;i<4;++i){
      float4 ov = make_float4(acc[i][0], acc[i][1], acc[i][2], acc[i][3]);
      *(float4*)&g[(ti*4+i)*DD + tj*4] = ov;
    }
  }
}

// ================= K2: combined register-wave QR (block 16) + expm (blocks 0..15) ==========
__device__ void qr_wave(const float* __restrict__ Gpart, const float* __restrict__ P,
                        float* __restrict__ Rout){
  const int j = threadIdx.x; // lane = column j
  float Gc[DD], Wc[DD], Rc[DD];
  #pragma unroll
  for (int i = 0; i < DD; ++i){
    float g = 0.f;
    #pragma unroll
    for (int p = 0; p < GPARTS; ++p) g += Gpart[p*4096 + i*DD + j];
    Gc[i] = g;
    Wc[i] = P[i*DD + j];
  }
  #pragma unroll
  for (int k = 0; k < DD; ++k){
    const float gkk = __shfl(Gc[k], k);
    const float wkk = __shfl(Wc[k], k);
    const float beta = (wkk >= 0.f) ? -sqrtf(gkk) : sqrtf(gkk);
    const float wkj = Wc[k];
    const float dj  = Gc[k] - beta*wkj;
    const float cj  = dj / (beta*(beta - wkk));
    float rkj = wkj + dj/beta;
    if (j == k) rkj = beta;
    if (j <  k) rkj = 0.f;
    Rc[k] = rkj;
    #pragma unroll
    for (int i = k+1; i < DD; ++i){
      const float wik = __shfl(Wc[i], k);   // column k of Wt lives in lane k
      const float rki = __shfl(rkj, i);     // R[k][i] lives in lane i
      Wc[i] = fmaf(-cj,  wik, Wc[i]);
      Gc[i] = fmaf(-rki, rkj, Gc[i]);
    }
  }
  #pragma unroll
  for (int i = 0; i < DD; ++i) Rout[i*DD + j] = Rc[i];
}

__device__ __forceinline__ void mmul68(const float* __restrict__ A, const float* __restrict__ B,
                                       float* __restrict__ C, int tid){
  __syncthreads();
  const int ty = tid >> 4, tx = tid & 15;
  float acc[4][4];
  #pragma unroll
  for (int i=0;i<4;++i){
    #pragma unroll
    for (int j=0;j<4;++j) acc[i][j]=0.f;
  }
  for (int kq = 0; kq < 16; ++kq){
    float4 a[4], b[4];
    #pragma unroll
    for (int i=0;i<4;++i) a[i] = *(const float4*)&A[(ty*4+i)*68 + kq*4];
    #pragma unroll
    for (int kk=0;kk<4;++kk) b[kk] = *(const float4*)&B[(kq*4+kk)*68 + tx*4];
    #pragma unroll
    for (int i=0;i<4;++i){
      const float av[4] = {a[i].x, a[i].y, a[i].z, a[i].w};
      #pragma unroll
      for (int kk=0;kk<4;++kk){
        acc[i][0] = fmaf(av[kk], b[kk].x, acc[i][0]);
        acc[i][1] = fmaf(av[kk], b[kk].y, acc[i][1]);
        acc[i][2] = fmaf(av[kk], b[kk].z, acc[i][2]);
        acc[i][3] = fmaf(av[kk], b[kk].w, acc[i][3]);
      }
    }
  }
  #pragma unroll
  for (int i=0;i<4;++i)
    *(float4*)&C[(ty*4+i)*68 + tx*4] = make_float4(acc[i][0],acc[i][1],acc[i][2],acc[i][3]);
  __syncthreads();
}

__global__ __launch_bounds__(256,1) void k_setup(const float* __restrict__ Gpart, const float* __restrict__ P,
                                                 float* __restrict__ Rout,
                                                 const float* __restrict__ v, float* __restrict__ Mg){
  __shared__ float Bs[64*68], B2[64*68], B3[64*68], Tb[64*68], Xb[64*68];
  __shared__ float ncol[DD];
  __shared__ float scl_s;
  __shared__ int   ssh_s;
  const int tid = threadIdx.x;
  if (blockIdx.x == NB){
    if (tid >= 64) return;
    qr_wave(Gpart, P, Rout);
    return;
  }
  const int b = blockIdx.x;
  // build skew A (unscaled) into Xb
  for (int idx = tid; idx < 64*64; idx += 256)
    Xb[(idx>>6)*68 + (idx&63)] = 0.f;
  __syncthreads();
  for (int idx = tid; idx < NSK; idx += 256){
    int i = (int)((127.0f - sqrtf(16129.0f - 8.0f*(float)idx)) * 0.5f);
    while (i*(127 - i)/2 > idx) --i;
    while ((i+1)*(127 - (i+1))/2 <= idx) ++i;
    const int jj = idx - i*(127 - i)/2 + i + 1;
    const float val = v[b*NSK + idx];
    Xb[i*68 + jj] = val;
    Xb[jj*68 + i] = -val;
  }
  __syncthreads();
  if (tid < DD){
    float s = 0.f;
    for (int r = 0; r < DD; ++r) s += fabsf(Xb[r*68 + tid]);
    ncol[tid] = s;
  }
  __syncthreads();
  if (tid == 0){
    float nrm = 0.f;
    for (int c = 0; c < DD; ++c) nrm = fmaxf(nrm, ncol[c]);
    int s = 0; float scale = 1.f;
    while (nrm > 1.0f && s < 40){ nrm *= 0.5f; scale *= 0.5f; ++s; }
    ssh_s = s; scl_s = scale;
  }
  __syncthreads();
  const float scale = scl_s;
  const int   sq    = ssh_s;
  for (int idx = tid; idx < 64*64; idx += 256){
    const int i = idx>>6, jj = idx&63;
    Bs[i*68 + jj] = Xb[i*68 + jj] * scale;
  }
  // B2 = B*B ; B3 = B2*B
  mmul68(Bs, Bs, B2, tid);
  mmul68(B2, Bs, B3, tid);
  // T = G2 + c9*B3 ; G2 = I/720 + B/5040 + B2/40320
  for (int idx = tid; idx < 64*64; idx += 256){
    const int i = idx>>6, jj = idx&63;
    const int o = i*68 + jj;
    Tb[o] = (i==jj ? (1.f/720.f) : 0.f) + Bs[o]*(1.f/5040.f) + B2[o]*(1.f/40320.f) + B3[o]*(1.f/362880.f);
  }
  mmul68(B3, Tb, Xb, tid);              // X = B3*T
  for (int idx = tid; idx < 64*64; idx += 256){
    const int i = idx>>6, jj = idx&63;
    const int o = i*68 + jj;
    Xb[o] += (i==jj ? (1.f/6.f) : 0.f) + Bs[o]*(1.f/24.f) + B2[o]*(1.f/120.f);
  }
  mmul68(B3, Xb, Tb, tid);              // T = B3*X
  for (int idx = tid; idx < 64*64; idx += 256){
    const int i = idx>>6, jj = idx&63;
    const int o = i*68 + jj;
    Tb[o] += (i==jj ? 1.f : 0.f) + Bs[o] + B2[o]*0.5f;   // + G0
  }
  // squarings
  float* cur = Tb;
  float* oth = Xb;
  for (int r = 0; r < sq; ++r){
    mmul68(cur, cur, oth, tid);
    float* t = cur; cur = oth; oth = t;
  }
  for (int idx = tid; idx < 64*64; idx += 256){
    const int i = idx>>6, jj = idx&63;
    Mg[b*4096 + idx] = cur[i*68 + jj] - (i==jj ? 1.f : 0.f);
  }
}

// ================= K3: solve u.R = p per row; emit U bf16 (row-major) + U^T bf16 ==========
__global__ __launch_bounds__(64) void k_solveU(const float* __restrict__ P, const float* __restrict__ Rg,
                                               short* __restrict__ Ubf, short* __restrict__ Utbf){
  __shared__ float Rs[DD*DD];
  __shared__ float Ps[DD*65];
  __shared__ float rd[DD];
  const int tid = threadIdx.x;
  const int n0 = blockIdx.x * DD;
  for (int r = 0; r < DD; ++r){
    Rs[r*DD + tid] = Rg[r*DD + tid];
    Ps[r*65 + tid] = P[(n0 + r)*DD + tid];
  }
  rd[tid] = 1.f / Rg[tid*DD + tid];
  __syncthreads();
  float u[DD];
  #pragma unroll
  for (int j = 0; j < DD; ++j){
    float s0 = Ps[tid*65 + j], s1 = 0.f;
    #pragma unroll
    for (int l = 0; l + 1 < j; l += 2){
      s0 = fmaf(-u[l],   Rs[l*DD + j],     s0);
      s1 = fmaf(-u[l+1], Rs[(l+1)*DD + j], s1);
    }
    if (j & 1) s0 = fmaf(-u[j-1], Rs[(j-1)*DD + j], s0);
    u[j] = (s0 + s1) * rd[j];
  }
  // U^T bf16 [64][1152]: coalesced per d
  #pragma unroll
  for (int d = 0; d < DD; ++d)
    Utbf[d*NN + n0 + tid] = bfr(u[d]);
  // U bf16 row-major [1152][64]: per-lane 16B vector stores of own row
  #pragma unroll
  for (int j8 = 0; j8 < 8; ++j8){
    bf16x8 pk;
    #pragma unroll
    for (int jj = 0; jj < 8; ++jj) pk[jj] = bfr(u[j8*8 + jj]);
    *(bf16x8*)&Ubf[(n0 + tid)*DD + j8*8] = pk;
  }
}

// ================= K4: fused main (16-row tiles, 256 thr, deep-pipelined) ==========
#define PH1_STEP(XA,XB,UU) do { \
    bf16x8 a_; \
    a_[0]=bfr(XA.x); a_[1]=bfr(XA.y); a_[2]=bfr(XA.z); a_[3]=bfr(XA.w); \
    a_[4]=bfr(XB.x); a_[5]=bfr(XB.y); a_[6]=bfr(XB.z); a_[7]=bfr(XB.w); \
    acc0 = __builtin_amdgcn_mfma_f32_16x16x32_bf16(a_, UU, acc0, 0, 0, 0); \
  } while(0)

#define PH3_BODY(NC) do { \
    const float xq0 = x[(row0 + quad*4 + 0)*NN + (NC) + m]; \
    const float xq1 = x[(row0 + quad*4 + 1)*NN + (NC) + m]; \
    const float xq2 = x[(row0 + quad*4 + 2)*NN + (NC) + m]; \
    const float xq3 = x[(row0 + quad*4 + 3)*NN + (NC) + m]; \
    f32x4 acc = {0.f,0.f,0.f,0.f}; \
    acc = __builtin_amdgcn_mfma_f32_16x16x32_bf16(wa0, ub0, acc, 0, 0, 0); \
    acc = __builtin_amdgcn_mfma_f32_16x16x32_bf16(wa1, ub1, acc, 0, 0, 0); \
    out[(row0 + quad*4 + 0)*NN + (NC) + m] = xq0 + acc[0]; \
    out[(row0 + quad*4 + 1)*NN + (NC) + m] = xq1 + acc[1]; \
    out[(row0 + quad*4 + 2)*NN + (NC) + m] = xq2 + acc[2]; \
    out[(row0 + quad*4 + 3)*NN + (NC) + m] = xq3 + acc[3]; \
  } while(0)

__global__ __launch_bounds__(256,4) void k_main(const float* __restrict__ x, const short* __restrict__ Ubf,
                                                const short* __restrict__ Utbf, const float* __restrict__ Mg,
                                                float* __restrict__ out){
  __shared__ float Ms[64*68];
  __shared__ float zs[16*68];
  __shared__ short wbf[16*72];
  const int tid  = threadIdx.x;
  const int lane = tid & 63, wid = tid >> 6;
  const int row0 = blockIdx.x * 16;
  const int bb   = row0 >> 10;
  const int m    = lane & 15, quad = lane >> 4;
  // stage M = (R-I) for this batch
  for (int idx = tid; idx < 64*64; idx += 256)
    Ms[(idx>>6)*68 + (idx&63)] = Mg[bb*4096 + idx];

  // ---- phase 1: z = x_tile(16x1152) @ U ; wave wid owns cols wid*16..+15
  const int c0 = wid * 16;
  const float* xrow = &x[(row0 + m)*NN + quad*8];
  const short* utp  = &Utbf[(c0 + m)*NN + quad*8];
  f32x4 acc0 = {0.f,0.f,0.f,0.f};
  float4 xa0 = *(const float4*)(xrow);
  float4 xb0 = *(const float4*)(xrow + 4);
  float4 xa1 = *(const float4*)(xrow + 32);
  float4 xb1 = *(const float4*)(xrow + 36);
  bf16x8 u0  = *(const bf16x8*)(utp);
  bf16x8 u1  = *(const bf16x8*)(utp + 32);
  for (int kc = 0; kc < NN - 64; kc += 64){
    const float4 pxa0 = *(const float4*)(xrow + kc + 64);
    const float4 pxb0 = *(const float4*)(xrow + kc + 68);
    const bf16x8 pu0  = *(const bf16x8*)(utp + kc + 64);
    const float4 pxa1 = *(const float4*)(xrow + kc + 96);
    const float4 pxb1 = *(const float4*)(xrow + kc + 100);
    const bf16x8 pu1  = *(const bf16x8*)(utp + kc + 96);
    PH1_STEP(xa0, xb0, u0);
    PH1_STEP(xa1, xb1, u1);
    xa0 = pxa0; xb0 = pxb0; u0 = pu0;
    xa1 = pxa1; xb1 = pxb1; u1 = pu1;
  }
  PH1_STEP(xa0, xb0, u0);
  PH1_STEP(xa1, xb1, u1);
  #pragma unroll
  for (int q = 0; q < 4; ++q)
    zs[(quad*4 + q)*68 + c0 + m] = acc0[q];
  __syncthreads();

  // ---- phase 2: w(16x64) = z @ M (fp32), store bf16
  {
    const int r  = tid >> 4;
    const int cc = (tid & 15) * 4;
    float w0[4] = {0.f,0.f,0.f,0.f};
    for (int k = 0; k < 64; ++k){
      const float zr = zs[r*68 + k];
      const float4 m0 = *(const float4*)&Ms[k*68 + cc];
      w0[0] = fmaf(zr, m0.x, w0[0]);
      w0[1] = fmaf(zr, m0.y, w0[1]);
      w0[2] = fmaf(zr, m0.z, w0[2]);
      w0[3] = fmaf(zr, m0.w, w0[3]);
    }
    bf16x4 pk;
    #pragma unroll
    for (int jj = 0; jj < 4; ++jj) pk[jj] = bfr(w0[jj]);
    *(bf16x4*)&wbf[r*72 + cc] = pk;
  }
  __syncthreads();

  // ---- phase 3: out = x + w @ U^T ; wave wid owns col-tiles wid+4*it
  bf16x8 wa0 = *(const bf16x8*)&wbf[m*72 +      quad*8];
  bf16x8 wa1 = *(const bf16x8*)&wbf[m*72 + 32 + quad*8];
  bf16x8 ub0 = *(const bf16x8*)&Ubf[(wid*16 + m)*DD +      quad*8];
  bf16x8 ub1 = *(const bf16x8*)&Ubf[(wid*16 + m)*DD + 32 + quad*8];
  for (int it = 0; it < 17; ++it){
    const int n0c = (wid + 4*it) * 16;
    const int n1  = n0c + 64;
    const bf16x8 nb0 = *(const bf16x8*)&Ubf[(n1 + m)*DD +      quad*8];
    const bf16x8 nb1 = *(const bf16x8*)&Ubf[(n1 + m)*DD + 32 + quad*8];
    PH3_BODY(n0c);
    ub0 = nb0; ub1 = nb1;
  }
  PH3_BODY((wid + 68) * 16);
}

extern "C" void kernel_launch(void* const* d_in, const int* in_sizes, int n_in,
                              void* d_out, int out_size, void* d_ws, size_t ws_size,
                              hipStream_t stream) {
  const float* x    = (const float*)d_in[0];
  const float* cond = (const float*)d_in[1];
  const float* P    = (const float*)d_in[2];
  const float* W    = (const float*)d_in[3];
  const float* bias = (const float*)d_in[4];
  float* out = (float*)d_out;
  float* ws  = (float*)d_ws;

  float* Gpart = ws;               // 6*4096 = 24576
  float* Rbuf  = ws + 24576;       // 4096
  float* vbuf  = ws + 28672;       // 32256
  float* Mg    = ws + 61440;       // 65536
  short* Ubf   = (short*)(ws + 126976);   // 1152*64 bf16
  short* Utbf  = (short*)(ws + 163840);   // 64*1152 bf16

  hipLaunchKernelGGL(k_pre,   dim3(VPB + GPARTS), dim3(256), 0, stream, cond, W, bias, vbuf, P, Gpart);
  hipLaunchKernelGGL(k_setup, dim3(NB + 1),       dim3(256), 0, stream, Gpart, P, Rbuf, vbuf, Mg);
  hipLaunchKernelGGL(k_solveU,dim3(NN/DD),        dim3(64),  0, stream, P, Rbuf, Ubf, Utbf);
  hipLaunchKernelGGL(k_main,  dim3(NROWS/16),     dim3(256), 0, stream, x, Ubf, Utbf, Mg, out);
}

// Round 2
// 265.675 us; speedup vs baseline: 1.2026x; 1.2026x over previous
//
#include <hip/hip_runtime.h>
#include <math.h>

#define NN 1152
#define DD 64
#define NSK 2016
#define NB 16
#define NROWS (NB*1024)
#define GPARTS 6
#define KPARTS 6
#define VNBLK 32
#define VBLKS (VNBLK*KPARTS)   // 192 vproj GEMM blocks

typedef short bf16x8 __attribute__((ext_vector_type(8)));
typedef short bf16x4 __attribute__((ext_vector_type(4)));
typedef float f32x4  __attribute__((ext_vector_type(4)));

__device__ __forceinline__ short bfr(float f){
  unsigned u = __float_as_uint(f);
  u += 0x7fffu + ((u >> 16) & 1u);
  return (short)(u >> 16);
}

// ================= K1: vproj as MFMA GEMM (blocks 0..191) + partial gram (192..197) ==========
// vpart[kp][b][q] partial sums; k_setup reduces over kp and adds bias.
__global__ __launch_bounds__(256) void k_pre(const float* __restrict__ cond, const float* __restrict__ W,
                                             float* __restrict__ vpart,
                                             const float* __restrict__ P, float* __restrict__ Gpart){
  __shared__ float Ps[64*68];
  const int tid = threadIdx.x;
  if (blockIdx.x < VBLKS){
    const int nb = blockIdx.x / KPARTS;
    const int kp = blockIdx.x % KPARTS;
    const int lane = tid & 63, wid = tid >> 6;
    const int m = lane & 15, quad = lane >> 4;
    const int n0 = nb*64 + wid*16;
    if (n0 >= NSK) return;            // tail tiles of last N-block
    f32x4 acc = {0.f,0.f,0.f,0.f};
    const float* crow = &cond[m*NN + kp*192 + quad*8];
    const float* wrow = &W[(n0 + m)*NN + kp*192 + quad*8];
    #pragma unroll
    for (int c = 0; c < 6; ++c){
      const float4 ca = *(const float4*)(crow + c*32);
      const float4 cb = *(const float4*)(crow + c*32 + 4);
      const float4 wa = *(const float4*)(wrow + c*32);
      const float4 wb = *(const float4*)(wrow + c*32 + 4);
      bf16x8 a, b;
      const float cv[8] = {ca.x,ca.y,ca.z,ca.w,cb.x,cb.y,cb.z,cb.w};
      const float wv[8] = {wa.x,wa.y,wa.z,wa.w,wb.x,wb.y,wb.z,wb.w};
      #pragma unroll
      for (int j = 0; j < 8; ++j){
        const float xv = cv[j];
        a[j] = bfr(xv / (1.f + __expf(-xv)));
        b[j] = bfr(wv[j]);
      }
      acc = __builtin_amdgcn_mfma_f32_16x16x32_bf16(a, b, acc, 0, 0, 0);
    }
    #pragma unroll
    for (int r = 0; r < 4; ++r)
      vpart[(kp*16 + quad*4 + r)*NSK + n0 + m] = acc[r];
  } else {
    // ---- partial gram: block p covers rows p*192 .. p*192+191 (3 chunks of 64)
    const int p = blockIdx.x - VBLKS;
    const int lr = tid >> 4, lc = (tid & 15) * 4;
    const int ti = tid >> 4, tj = tid & 15;
    float acc[4][4];
    #pragma unroll
    for (int i=0;i<4;++i){
      #pragma unroll
      for (int j=0;j<4;++j) acc[i][j]=0.f;
    }
    for (int ch = 0; ch < 3; ++ch){
      const int nn0 = p*192 + ch*64;
      __syncthreads();
      #pragma unroll
      for (int ii = 0; ii < 4; ++ii){
        const float4 pv = *(const float4*)&P[(nn0 + lr + 16*ii)*DD + lc];
        *(float4*)&Ps[(lr + 16*ii)*68 + lc] = pv;
      }
      __syncthreads();
      for (int r = 0; r < 64; ++r){
        const float4 a = *(const float4*)&Ps[r*68 + ti*4];
        const float4 b = *(const float4*)&Ps[r*68 + tj*4];
        const float av[4] = {a.x,a.y,a.z,a.w};
        const float bv[4] = {b.x,b.y,b.z,b.w};
        #pragma unroll
        for (int i=0;i<4;++i){
          #pragma unroll
          for (int j=0;j<4;++j) acc[i][j] = fmaf(av[i], bv[j], acc[i][j]);
        }
      }
    }
    float* g = &Gpart[p*DD*DD];
    #pragma unroll
    for (int i=0;i<4;++i){
      float4 ov = make_float4(acc[i][0], acc[i][1], acc[i][2], acc[i][3]);
      *(float4*)&g[(ti*4+i)*DD + tj*4] = ov;
    }
  }
}

// ================= K2: combined register-wave QR (block 16) + expm (blocks 0..15) ==========
__device__ void qr_wave(const float* __restrict__ Gpart, const float* __restrict__ P,
                        float* __restrict__ Rout){
  const int j = threadIdx.x; // lane = column j
  float Gc[DD], Wc[DD], Rc[DD];
  #pragma unroll
  for (int i = 0; i < DD; ++i){
    float g = 0.f;
    #pragma unroll
    for (int p = 0; p < GPARTS; ++p) g += Gpart[p*4096 + i*DD + j];
    Gc[i] = g;
    Wc[i] = P[i*DD + j];
  }
  #pragma unroll
  for (int k = 0; k < DD; ++k){
    const float gkk = __shfl(Gc[k], k);
    const float wkk = __shfl(Wc[k], k);
    const float beta = (wkk >= 0.f) ? -sqrtf(gkk) : sqrtf(gkk);
    const float wkj = Wc[k];
    const float dj  = Gc[k] - beta*wkj;
    const float cj  = dj / (beta*(beta - wkk));
    float rkj = wkj + dj/beta;
    if (j == k) rkj = beta;
    if (j <  k) rkj = 0.f;
    Rc[k] = rkj;
    #pragma unroll
    for (int i = k+1; i < DD; ++i){
      const float wik = __shfl(Wc[i], k);   // column k of Wt lives in lane k
      const float rki = __shfl(rkj, i);     // R[k][i] lives in lane i
      Wc[i] = fmaf(-cj,  wik, Wc[i]);
      Gc[i] = fmaf(-rki, rkj, Gc[i]);
    }
  }
  #pragma unroll
  for (int i = 0; i < DD; ++i) Rout[i*DD + j] = Rc[i];
}

__device__ __forceinline__ void mmul68(const float* __restrict__ A, const float* __restrict__ B,
                                       float* __restrict__ C, int tid){
  __syncthreads();
  const int ty = tid >> 4, tx = tid & 15;
  float acc[4][4];
  #pragma unroll
  for (int i=0;i<4;++i){
    #pragma unroll
    for (int j=0;j<4;++j) acc[i][j]=0.f;
  }
  for (int kq = 0; kq < 16; ++kq){
    float4 a[4], b[4];
    #pragma unroll
    for (int i=0;i<4;++i) a[i] = *(const float4*)&A[(ty*4+i)*68 + kq*4];
    #pragma unroll
    for (int kk=0;kk<4;++kk) b[kk] = *(const float4*)&B[(kq*4+kk)*68 + tx*4];
    #pragma unroll
    for (int i=0;i<4;++i){
      const float av[4] = {a[i].x, a[i].y, a[i].z, a[i].w};
      #pragma unroll
      for (int kk=0;kk<4;++kk){
        acc[i][0] = fmaf(av[kk], b[kk].x, acc[i][0]);
        acc[i][1] = fmaf(av[kk], b[kk].y, acc[i][1]);
        acc[i][2] = fmaf(av[kk], b[kk].z, acc[i][2]);
        acc[i][3] = fmaf(av[kk], b[kk].w, acc[i][3]);
      }
    }
  }
  #pragma unroll
  for (int i=0;i<4;++i)
    *(float4*)&C[(ty*4+i)*68 + tx*4] = make_float4(acc[i][0],acc[i][1],acc[i][2],acc[i][3]);
  __syncthreads();
}

__global__ __launch_bounds__(256,1) void k_setup(const float* __restrict__ Gpart, const float* __restrict__ P,
                                                 float* __restrict__ Rout,
                                                 const float* __restrict__ vpart, const float* __restrict__ bias,
                                                 float* __restrict__ Mg){
  __shared__ float Bs[64*68], B2[64*68], B3[64*68], Tb[64*68], Xb[64*68];
  __shared__ float ncol[DD];
  __shared__ float scl_s;
  __shared__ int   ssh_s;
  const int tid = threadIdx.x;
  if (blockIdx.x == NB){
    if (tid >= 64) return;
    qr_wave(Gpart, P, Rout);
    return;
  }
  const int b = blockIdx.x;
  // build skew A (unscaled) into Xb; v reduced over K-partials + bias
  for (int idx = tid; idx < 64*64; idx += 256)
    Xb[(idx>>6)*68 + (idx&63)] = 0.f;
  __syncthreads();
  for (int idx = tid; idx < NSK; idx += 256){
    int i = (int)((127.0f - sqrtf(16129.0f - 8.0f*(float)idx)) * 0.5f);
    while (i*(127 - i)/2 > idx) --i;
    while ((i+1)*(127 - (i+1))/2 <= idx) ++i;
    const int jj = idx - i*(127 - i)/2 + i + 1;
    float val = bias[idx];
    #pragma unroll
    for (int p = 0; p < KPARTS; ++p) val += vpart[(p*16 + b)*NSK + idx];
    Xb[i*68 + jj] = val;
    Xb[jj*68 + i] = -val;
  }
  __syncthreads();
  if (tid < DD){
    float s = 0.f;
    for (int r = 0; r < DD; ++r) s += fabsf(Xb[r*68 + tid]);
    ncol[tid] = s;
  }
  __syncthreads();
  if (tid == 0){
    float nrm = 0.f;
    for (int c = 0; c < DD; ++c) nrm = fmaxf(nrm, ncol[c]);
    int s = 0; float scale = 1.f;
    while (nrm > 1.0f && s < 40){ nrm *= 0.5f; scale *= 0.5f; ++s; }
    ssh_s = s; scl_s = scale;
  }
  __syncthreads();
  const float scale = scl_s;
  const int   sq    = ssh_s;
  for (int idx = tid; idx < 64*64; idx += 256){
    const int i = idx>>6, jj = idx&63;
    Bs[i*68 + jj] = Xb[i*68 + jj] * scale;
  }
  // B2 = B*B ; B3 = B2*B
  mmul68(Bs, Bs, B2, tid);
  mmul68(B2, Bs, B3, tid);
  for (int idx = tid; idx < 64*64; idx += 256){
    const int i = idx>>6, jj = idx&63;
    const int o = i*68 + jj;
    Tb[o] = (i==jj ? (1.f/720.f) : 0.f) + Bs[o]*(1.f/5040.f) + B2[o]*(1.f/40320.f) + B3[o]*(1.f/362880.f);
  }
  mmul68(B3, Tb, Xb, tid);              // X = B3*T
  for (int idx = tid; idx < 64*64; idx += 256){
    const int i = idx>>6, jj = idx&63;
    const int o = i*68 + jj;
    Xb[o] += (i==jj ? (1.f/6.f) : 0.f) + Bs[o]*(1.f/24.f) + B2[o]*(1.f/120.f);
  }
  mmul68(B3, Xb, Tb, tid);              // T = B3*X
  for (int idx = tid; idx < 64*64; idx += 256){
    const int i = idx>>6, jj = idx&63;
    const int o = i*68 + jj;
    Tb[o] += (i==jj ? 1.f : 0.f) + Bs[o] + B2[o]*0.5f;   // + G0
  }
  // squarings
  float* cur = Tb;
  float* oth = Xb;
  for (int r = 0; r < sq; ++r){
    mmul68(cur, cur, oth, tid);
    float* t = cur; cur = oth; oth = t;
  }
  for (int idx = tid; idx < 64*64; idx += 256){
    const int i = idx>>6, jj = idx&63;
    Mg[b*4096 + idx] = cur[i*68 + jj] - (i==jj ? 1.f : 0.f);
  }
}

// ================= K3: solve u.R = p per row; emit U bf16 (row-major) + U^T bf16 ==========
__global__ __launch_bounds__(64) void k_solveU(const float* __restrict__ P, const float* __restrict__ Rg,
                                               short* __restrict__ Ubf, short* __restrict__ Utbf){
  __shared__ float Rs[DD*DD];
  __shared__ float Ps[DD*65];
  __shared__ float rd[DD];
  const int tid = threadIdx.x;
  const int n0 = blockIdx.x * DD;
  for (int r = 0; r < DD; ++r){
    Rs[r*DD + tid] = Rg[r*DD + tid];
    Ps[r*65 + tid] = P[(n0 + r)*DD + tid];
  }
  rd[tid] = 1.f / Rg[tid*DD + tid];
  __syncthreads();
  float u[DD];
  #pragma unroll
  for (int j = 0; j < DD; ++j){
    float s0 = Ps[tid*65 + j], s1 = 0.f;
    #pragma unroll
    for (int l = 0; l + 1 < j; l += 2){
      s0 = fmaf(-u[l],   Rs[l*DD + j],     s0);
      s1 = fmaf(-u[l+1], Rs[(l+1)*DD + j], s1);
    }
    if (j & 1) s0 = fmaf(-u[j-1], Rs[(j-1)*DD + j], s0);
    u[j] = (s0 + s1) * rd[j];
  }
  #pragma unroll
  for (int d = 0; d < DD; ++d)
    Utbf[d*NN + n0 + tid] = bfr(u[d]);
  #pragma unroll
  for (int j8 = 0; j8 < 8; ++j8){
    bf16x8 pk;
    #pragma unroll
    for (int jj = 0; jj < 8; ++jj) pk[jj] = bfr(u[j8*8 + jj]);
    *(bf16x8*)&Ubf[(n0 + tid)*DD + j8*8] = pk;
  }
}

// ================= K4a: z = x.U ; w = z.(R-I) -> wg bf16 (round-0 p1+p2 structure) ==========
__global__ __launch_bounds__(512,1) void k_zw(const float* __restrict__ x, const short* __restrict__ Utbf,
                                              const float* __restrict__ Mg, short* __restrict__ wg){
  __shared__ float zs[64*68];
  __shared__ float Ms[64*68];
  const int tid  = threadIdx.x;
  const int lane = tid & 63, wid = tid >> 6;
  const int row0 = blockIdx.x * 64;
  const int bb   = row0 >> 10;
  const int m    = lane & 15, quad = lane >> 4;
  for (int idx = tid; idx < 64*64; idx += 512)
    Ms[(idx>>6)*68 + (idx&63)] = Mg[bb*4096 + idx];

  // ---- phase 1: z = x_tile @ U   (wave: rows (wid&3)*16, cols (wid>>2)*32)
  const int r0 = (wid & 3) * 16;
  const int c0 = (wid >> 2) * 32;
  f32x4 acc0 = {0.f,0.f,0.f,0.f}, acc1 = {0.f,0.f,0.f,0.f};
  const float* xrow = &x[(row0 + r0 + m)*NN + quad*8];
  const short* ut0  = &Utbf[(c0      + m)*NN + quad*8];
  const short* ut1  = &Utbf[(c0 + 16 + m)*NN + quad*8];
  float4 xa = *(const float4*)(xrow);
  float4 xb = *(const float4*)(xrow + 4);
  bf16x8 b0 = *(const bf16x8*)(ut0);
  bf16x8 b1 = *(const bf16x8*)(ut1);
  for (int kc = 0; kc < NN; kc += 32){
    float4 nxa, nxb; bf16x8 nb0, nb1;
    if (kc + 32 < NN){
      nxa = *(const float4*)(xrow + kc + 32);
      nxb = *(const float4*)(xrow + kc + 36);
      nb0 = *(const bf16x8*)(ut0 + kc + 32);
      nb1 = *(const bf16x8*)(ut1 + kc + 32);
    }
    bf16x8 a;
    a[0]=bfr(xa.x); a[1]=bfr(xa.y); a[2]=bfr(xa.z); a[3]=bfr(xa.w);
    a[4]=bfr(xb.x); a[5]=bfr(xb.y); a[6]=bfr(xb.z); a[7]=bfr(xb.w);
    acc0 = __builtin_amdgcn_mfma_f32_16x16x32_bf16(a, b0, acc0, 0, 0, 0);
    acc1 = __builtin_amdgcn_mfma_f32_16x16x32_bf16(a, b1, acc1, 0, 0, 0);
    xa = nxa; xb = nxb; b0 = nb0; b1 = nb1;
  }
  #pragma unroll
  for (int q = 0; q < 4; ++q){
    zs[(r0 + quad*4 + q)*68 + c0      + m] = acc0[q];
    zs[(r0 + quad*4 + q)*68 + c0 + 16 + m] = acc1[q];
  }
  __syncthreads();

  // ---- phase 2: w = z @ M (fp32), store bf16 to global
  const int r  = tid >> 3;
  const int cc = (tid & 7) * 8;
  float w0[8];
  #pragma unroll
  for (int jj = 0; jj < 8; ++jj) w0[jj] = 0.f;
  for (int k = 0; k < 64; ++k){
    const float zr = zs[r*68 + k];
    const float4 m0 = *(const float4*)&Ms[k*68 + cc];
    const float4 m1 = *(const float4*)&Ms[k*68 + cc + 4];
    w0[0] = fmaf(zr, m0.x, w0[0]); w0[1] = fmaf(zr, m0.y, w0[1]);
    w0[2] = fmaf(zr, m0.z, w0[2]); w0[3] = fmaf(zr, m0.w, w0[3]);
    w0[4] = fmaf(zr, m1.x, w0[4]); w0[5] = fmaf(zr, m1.y, w0[5]);
    w0[6] = fmaf(zr, m1.z, w0[6]); w0[7] = fmaf(zr, m1.w, w0[7]);
  }
  bf16x8 pk;
  #pragma unroll
  for (int jj = 0; jj < 8; ++jj) pk[jj] = bfr(w0[jj]);
  *(bf16x8*)&wg[(row0 + r)*DD + cc] = pk;
}

// ================= K4b: out = x + w @ U^T  (pure streaming, 16 rows/block, 16 waves/CU) ==========
__global__ __launch_bounds__(256) void k_out(const float* __restrict__ x, const short* __restrict__ Ubf,
                                             const short* __restrict__ wg, float* __restrict__ out){
  const int tid  = threadIdx.x;
  const int lane = tid & 63, wid = tid >> 6;
  const int row0 = blockIdx.x * 16;
  const int m    = lane & 15, quad = lane >> 4;
  const int q4   = quad * 4;
  bf16x8 wa0 = *(const bf16x8*)&wg[(row0 + m)*DD +      quad*8];
  bf16x8 wa1 = *(const bf16x8*)&wg[(row0 + m)*DD + 32 + quad*8];
  bf16x8 ub0 = *(const bf16x8*)&Ubf[(wid*16 + m)*DD +      quad*8];
  bf16x8 ub1 = *(const bf16x8*)&Ubf[(wid*16 + m)*DD + 32 + quad*8];
  float xq0 = x[(row0 + q4 + 0)*NN + wid*16 + m];
  float xq1 = x[(row0 + q4 + 1)*NN + wid*16 + m];
  float xq2 = x[(row0 + q4 + 2)*NN + wid*16 + m];
  float xq3 = x[(row0 + q4 + 3)*NN + wid*16 + m];
  for (int it = 0; it < 18; ++it){
    const int n0 = (wid + 4*it) * 16;
    f32x4 acc = {0.f,0.f,0.f,0.f};
    acc = __builtin_amdgcn_mfma_f32_16x16x32_bf16(wa0, ub0, acc, 0, 0, 0);
    acc = __builtin_amdgcn_mfma_f32_16x16x32_bf16(wa1, ub1, acc, 0, 0, 0);
    const float o0 = xq0 + acc[0];
    const float o1 = xq1 + acc[1];
    const float o2 = xq2 + acc[2];
    const float o3 = xq3 + acc[3];
    if (it < 17){
      const int n1 = n0 + 64;
      ub0 = *(const bf16x8*)&Ubf[(n1 + m)*DD +      quad*8];
      ub1 = *(const bf16x8*)&Ubf[(n1 + m)*DD + 32 + quad*8];
      xq0 = x[(row0 + q4 + 0)*NN + n1 + m];
      xq1 = x[(row0 + q4 + 1)*NN + n1 + m];
      xq2 = x[(row0 + q4 + 2)*NN + n1 + m];
      xq3 = x[(row0 + q4 + 3)*NN + n1 + m];
    }
    out[(row0 + q4 + 0)*NN + n0 + m] = o0;
    out[(row0 + q4 + 1)*NN + n0 + m] = o1;
    out[(row0 + q4 + 2)*NN + n0 + m] = o2;
    out[(row0 + q4 + 3)*NN + n0 + m] = o3;
  }
}

extern "C" void kernel_launch(void* const* d_in, const int* in_sizes, int n_in,
                              void* d_out, int out_size, void* d_ws, size_t ws_size,
                              hipStream_t stream) {
  const float* x    = (const float*)d_in[0];
  const float* cond = (const float*)d_in[1];
  const float* P    = (const float*)d_in[2];
  const float* W    = (const float*)d_in[3];
  const float* bias = (const float*)d_in[4];
  float* out = (float*)d_out;
  float* ws  = (float*)d_ws;

  float* Gpart = ws;                      // 6*4096 = 24576 floats
  float* Rbuf  = ws + 24576;              // 4096
  float* vpart = ws + 28672;              // 6*16*2016 = 193536
  float* Mg    = ws + 222208;             // 16*4096 = 65536
  short* Ubf   = (short*)(ws + 287744);   // 1152*64 bf16 = 36864 floats
  short* Utbf  = (short*)(ws + 324608);   // 64*1152 bf16 = 36864 floats
  short* wg    = (short*)(ws + 361472);   // 16384*64 bf16 = 524288 floats

  hipLaunchKernelGGL(k_pre,   dim3(VBLKS + GPARTS), dim3(256), 0, stream, cond, W, vpart, P, Gpart);
  hipLaunchKernelGGL(k_setup, dim3(NB + 1),         dim3(256), 0, stream, Gpart, P, Rbuf, vpart, bias, Mg);
  hipLaunchKernelGGL(k_solveU,dim3(NN/DD),          dim3(64),  0, stream, P, Rbuf, Ubf, Utbf);
  hipLaunchKernelGGL(k_zw,    dim3(NROWS/64),       dim3(512), 0, stream, x, Utbf, Mg, wg);
  hipLaunchKernelGGL(k_out,   dim3(NROWS/16),       dim3(256), 0, stream, x, Ubf, wg, out);
}